// Round 2
// baseline (3778.149 us; speedup 1.0000x reference)
//
#include <hip/hip_runtime.h>
#include <cstdint>

#define Hn 36
#define G4 144          // 4*H gate rows
#define TT 512
#define BB 2048

__device__ __forceinline__ float sigf(float x) { return 1.0f / (1.0f + __expf(-x)); }
__device__ __forceinline__ float tanh_fast(float x) {
    float e = __expf(2.0f * x);          // exact +-1 limits via over/underflow
    return 1.0f - 2.0f / (e + 1.0f);
}

// dot products: W is a register array (constant indices only!), H is an LDS
// pointer read wave-uniformly (float4 broadcast, conflict-free).
#define DOT36(W, H, Z0, Z1, Z2, Z3)                        \
    do {                                                   \
        _Pragma("unroll") for (int _k = 0; _k < 9; ++_k) { \
            float4 hv = *(const float4*)&(H)[_k * 4];      \
            Z0 = fmaf((W)[_k * 4 + 0], hv.x, Z0);          \
            Z1 = fmaf((W)[_k * 4 + 1], hv.y, Z1);          \
            Z2 = fmaf((W)[_k * 4 + 2], hv.z, Z2);          \
            Z3 = fmaf((W)[_k * 4 + 3], hv.w, Z3);          \
        }                                                  \
    } while (0)

#define DOT72(W, H, Z0, Z1, Z2, Z3)                         \
    do {                                                    \
        _Pragma("unroll") for (int _k = 0; _k < 18; ++_k) { \
            float4 hv = *(const float4*)&(H)[_k * 4];       \
            Z0 = fmaf((W)[_k * 4 + 0], hv.x, Z0);           \
            Z1 = fmaf((W)[_k * 4 + 1], hv.y, Z1);           \
            Z2 = fmaf((W)[_k * 4 + 2], hv.z, Z2);           \
            Z3 = fmaf((W)[_k * 4 + 3], hv.w, Z3);           \
        }                                                   \
    } while (0)

// ======================= PRIMARY PATH (needs 151 MB ws) ======================
// Kernel 1: layer-0 reverse scan -> h0r (B, T, 36) fp32 in workspace.
#define CH0 4
#define NT0 (CH0 * G4)   // 576
__global__ __launch_bounds__(NT0) void l0rev_kernel(
    const float* __restrict__ x,
    const float* __restrict__ Wih, const float* __restrict__ Whh,
    const float* __restrict__ bih, const float* __restrict__ bhh,
    float* __restrict__ h0r)
{
    const int tid = threadIdx.x;
    const int cc  = tid / G4;
    const int g   = tid % G4;
    const int b   = blockIdx.x * CH0 + cc;

    __shared__ float xs[CH0][TT];
    __shared__ float hs[CH0][40];
    __shared__ float zs[CH0][G4];

    for (int i = g; i < TT; i += G4) xs[cc][i] = x[(size_t)b * TT + i];

    float w[Hn];
#pragma unroll
    for (int k = 0; k < Hn; ++k) w[k] = Whh[g * Hn + k];
    const float wx   = Wih[g];
    const float bias = bih[g] + bhh[g];

    if (g < Hn) hs[cc][g] = 0.0f;
    float c = 0.0f;
    __syncthreads();

    float* rrow = h0r + (size_t)b * TT * Hn;
    for (int s = 0; s < TT; ++s) {
        const int t = TT - 1 - s;
        float z0 = fmaf(xs[cc][t], wx, bias), z1 = 0.f, z2 = 0.f, z3 = 0.f;
        DOT36(w, hs[cc], z0, z1, z2, z3);
        zs[cc][g] = (z0 + z1) + (z2 + z3);
        __syncthreads();
        if (g < Hn) {
            float zi = zs[cc][g], zf = zs[cc][g + 36], zg = zs[cc][g + 72], zo = zs[cc][g + 108];
            c = sigf(zf) * c + sigf(zi) * tanh_fast(zg);
            float h = sigf(zo) * tanh_fast(c);
            hs[cc][g] = h;
            rrow[(size_t)t * Hn + g] = h;
        }
        __syncthreads();
    }
}

// Kernel 2: fused L0-forward + L1-forward scan + single-step L1-reverse + FC.
#define CH1 2
#define NT1 (CH1 * G4)   // 288
__global__ __launch_bounds__(NT1) void fused_fwd_kernel(
    const float* __restrict__ x,
    const float* __restrict__ Wih0f, const float* __restrict__ Whh0f,
    const float* __restrict__ bih0f, const float* __restrict__ bhh0f,
    const float* __restrict__ Wih1f, const float* __restrict__ Whh1f,
    const float* __restrict__ bih1f, const float* __restrict__ bhh1f,
    const float* __restrict__ Wih1r,
    const float* __restrict__ bih1r, const float* __restrict__ bhh1r,
    const float* __restrict__ fcW, const float* __restrict__ fcb,
    const float* __restrict__ h0r,
    float* __restrict__ out)
{
    const int tid = threadIdx.x;
    const int cc  = tid / G4;
    const int g   = tid % G4;
    const int b   = blockIdx.x * CH1 + cc;

    __shared__ float xs[CH1][TT];
    __shared__ float h0s[CH1][80];   // [h0f(36) | h0r(36)] = h0cat row
    __shared__ float hs1[CH1][40];
    __shared__ float zs[CH1][G4];
    __shared__ float red[CH1][40];

    for (int i = g; i < TT; i += G4) xs[cc][i] = x[(size_t)b * TT + i];

    float w0[Hn];
#pragma unroll
    for (int k = 0; k < Hn; ++k) w0[k] = Whh0f[g * Hn + k];
    const float wx0 = Wih0f[g];
    const float b0  = bih0f[g] + bhh0f[g];

    float w1i[72];
#pragma unroll
    for (int k = 0; k < 72; ++k) w1i[k] = Wih1f[g * 72 + k];
    float w1h[Hn];
#pragma unroll
    for (int k = 0; k < Hn; ++k) w1h[k] = Whh1f[g * Hn + k];
    const float b1 = bih1f[g] + bhh1f[g];

    if (g < Hn) { h0s[cc][g] = 0.0f; hs1[cc][g] = 0.0f; }
    float c0 = 0.0f, c1 = 0.0f;

    const float* rrow = h0r + (size_t)b * TT * Hn;
    float rv = (g >= 36 && g < 72) ? rrow[g - 36] : 0.0f;   // h0r(t=0)
    __syncthreads();

    for (int t = 0; t < TT; ++t) {
        // ---- phase A: layer-0 forward step ----
        float z0 = fmaf(xs[cc][t], wx0, b0), z1 = 0.f, z2 = 0.f, z3 = 0.f;
        DOT36(w0, h0s[cc], z0, z1, z2, z3);
        zs[cc][g] = (z0 + z1) + (z2 + z3);
        __syncthreads();
        if (g < Hn) {
            float zi = zs[cc][g], zf = zs[cc][g + 36], zg = zs[cc][g + 72], zo = zs[cc][g + 108];
            c0 = sigf(zf) * c0 + sigf(zi) * tanh_fast(zg);
            h0s[cc][g] = sigf(zo) * tanh_fast(c0);
        } else if (g < 72) {
            h0s[cc][g] = rv;                     // h0r(t), prefetched
        }
        __syncthreads();
        if (g >= 36 && g < 72 && t + 1 < TT)     // prefetch h0r(t+1)
            rv = rrow[(size_t)(t + 1) * Hn + (g - 36)];

        // ---- phase B: layer-1 forward step ----
        float y0 = b1, y1 = 0.f, y2 = 0.f, y3 = 0.f;
        DOT72(w1i, h0s[cc], y0, y1, y2, y3);
        DOT36(w1h, hs1[cc], y0, y1, y2, y3);
        zs[cc][g] = (y0 + y1) + (y2 + y3);
        __syncthreads();
        if (g < Hn) {
            float zi = zs[cc][g], zf = zs[cc][g + 36], zg = zs[cc][g + 72], zo = zs[cc][g + 108];
            c1 = sigf(zf) * c1 + sigf(zi) * tanh_fast(zg);
            hs1[cc][g] = sigf(zo) * tanh_fast(c1);
        }
        __syncthreads();
    }

    // ---- tail: L1 reverse single step at t=T-1 (h0=c0=0) + FC ----
    float zR = bih1r[g] + bhh1r[g];
#pragma unroll
    for (int k = 0; k < 72; ++k) zR = fmaf(Wih1r[g * 72 + k], h0s[cc][k], zR);
    zs[cc][g] = zR;
    __syncthreads();
    if (g < Hn) {
        float zi = zs[cc][g], zg = zs[cc][g + 72], zo = zs[cc][g + 108];
        float c  = sigf(zi) * tanh_fast(zg);     // c0=0: forget term vanishes
        float hr = sigf(zo) * tanh_fast(c);
        red[cc][g] = fcW[36 + g] * hr + fcW[g] * hs1[cc][g];
    }
    __syncthreads();
    if (g == 0) {
        float s = fcb[0];
        for (int j = 0; j < Hn; ++j) s += red[cc][j];
        out[b] = s;
    }
}

// ================= FALLBACK PATH (zero workspace, ckpt/recompute) ============
__global__ __launch_bounds__(G4) void fused_all_kernel(
    const float* __restrict__ x,
    const float* __restrict__ Wih0f, const float* __restrict__ Whh0f,
    const float* __restrict__ bih0f, const float* __restrict__ bhh0f,
    const float* __restrict__ Wih0r, const float* __restrict__ Whh0r,
    const float* __restrict__ bih0r, const float* __restrict__ bhh0r,
    const float* __restrict__ Wih1f, const float* __restrict__ Whh1f,
    const float* __restrict__ bih1f, const float* __restrict__ bhh1f,
    const float* __restrict__ Wih1r,
    const float* __restrict__ bih1r, const float* __restrict__ bhh1r,
    const float* __restrict__ fcW, const float* __restrict__ fcb,
    float* __restrict__ out)
{
    const int g = threadIdx.x;
    const int b = blockIdx.x;

    __shared__ float xs[TT];
    __shared__ float cbuf[64][Hn];        // one 64-step chunk of h0r
    __shared__ float ckpt_h[8][Hn], ckpt_c[8][Hn];
    __shared__ float hr[40], h0s[80], hs1[40], zs[G4], red[40];

    for (int i = g; i < TT; i += G4) xs[i] = x[(size_t)b * TT + i];

    float wr[Hn], wf[Hn];
#pragma unroll
    for (int k = 0; k < Hn; ++k) wr[k] = Whh0r[g * Hn + k];
#pragma unroll
    for (int k = 0; k < Hn; ++k) wf[k] = Whh0f[g * Hn + k];
    const float wxr = Wih0r[g], br = bih0r[g] + bhh0r[g];
    const float wxf = Wih0f[g], bf = bih0f[g] + bhh0f[g];
    float w1i[72];
#pragma unroll
    for (int k = 0; k < 72; ++k) w1i[k] = Wih1f[g * 72 + k];
    float w1h[Hn];
#pragma unroll
    for (int k = 0; k < Hn; ++k) w1h[k] = Whh1f[g * Hn + k];
    const float b1 = bih1f[g] + bhh1f[g];

    // ---- pass 1: full reverse scan, saving (h,c) checkpoints ----
    if (g < Hn) hr[g] = 0.0f;
    float cr = 0.0f;
    __syncthreads();
    for (int s = 0; s < TT; ++s) {
        const int t = TT - 1 - s;
        if ((t & 63) == 63 && g < Hn) { ckpt_h[t >> 6][g] = hr[g]; ckpt_c[t >> 6][g] = cr; }
        float z0 = fmaf(xs[t], wxr, br), z1 = 0.f, z2 = 0.f, z3 = 0.f;
        DOT36(wr, hr, z0, z1, z2, z3);
        zs[g] = (z0 + z1) + (z2 + z3);
        __syncthreads();
        if (g < Hn) {
            float zi = zs[g], zf = zs[g + 36], zg = zs[g + 72], zo = zs[g + 108];
            cr = sigf(zf) * cr + sigf(zi) * tanh_fast(zg);
            hr[g] = sigf(zo) * tanh_fast(cr);
        }
        __syncthreads();
    }

    // ---- pass 2: per chunk, recompute reverse then run fused forward ----
    if (g < Hn) { h0s[g] = 0.0f; hs1[g] = 0.0f; }
    float c0 = 0.0f, c1 = 0.0f;
    __syncthreads();

    for (int m = 0; m < 8; ++m) {
        if (g < Hn) { hr[g] = ckpt_h[m][g]; cr = ckpt_c[m][g]; }
        __syncthreads();
        for (int j = 0; j < 64; ++j) {
            const int t = m * 64 + 63 - j;
            float z0 = fmaf(xs[t], wxr, br), z1 = 0.f, z2 = 0.f, z3 = 0.f;
            DOT36(wr, hr, z0, z1, z2, z3);
            zs[g] = (z0 + z1) + (z2 + z3);
            __syncthreads();
            if (g < Hn) {
                float zi = zs[g], zf = zs[g + 36], zg = zs[g + 72], zo = zs[g + 108];
                cr = sigf(zf) * cr + sigf(zi) * tanh_fast(zg);
                float h = sigf(zo) * tanh_fast(cr);
                hr[g] = h;
                cbuf[t & 63][g] = h;
            }
            __syncthreads();
        }
        for (int j = 0; j < 64; ++j) {
            const int t = m * 64 + j;
            float z0 = fmaf(xs[t], wxf, bf), z1 = 0.f, z2 = 0.f, z3 = 0.f;
            DOT36(wf, h0s, z0, z1, z2, z3);
            zs[g] = (z0 + z1) + (z2 + z3);
            __syncthreads();
            if (g < Hn) {
                float zi = zs[g], zf = zs[g + 36], zg = zs[g + 72], zo = zs[g + 108];
                c0 = sigf(zf) * c0 + sigf(zi) * tanh_fast(zg);
                h0s[g] = sigf(zo) * tanh_fast(c0);
            } else if (g < 72) {
                h0s[g] = cbuf[j][g - 36];
            }
            __syncthreads();
            float y0 = b1, y1 = 0.f, y2 = 0.f, y3 = 0.f;
            DOT72(w1i, h0s, y0, y1, y2, y3);
            DOT36(w1h, hs1, y0, y1, y2, y3);
            zs[g] = (y0 + y1) + (y2 + y3);
            __syncthreads();
            if (g < Hn) {
                float zi = zs[g], zf = zs[g + 36], zg = zs[g + 72], zo = zs[g + 108];
                c1 = sigf(zf) * c1 + sigf(zi) * tanh_fast(zg);
                hs1[g] = sigf(zo) * tanh_fast(c1);
            }
            __syncthreads();
        }
    }

    // ---- tail ----
    float zR = bih1r[g] + bhh1r[g];
#pragma unroll
    for (int k = 0; k < 72; ++k) zR = fmaf(Wih1r[g * 72 + k], h0s[k], zR);
    zs[g] = zR;
    __syncthreads();
    if (g < Hn) {
        float zi = zs[g], zg = zs[g + 72], zo = zs[g + 108];
        float c  = sigf(zi) * tanh_fast(zg);
        float hrv = sigf(zo) * tanh_fast(c);
        red[g] = fcW[36 + g] * hrv + fcW[g] * hs1[g];
    }
    __syncthreads();
    if (g == 0) {
        float s = fcb[0];
        for (int j = 0; j < Hn; ++j) s += red[j];
        out[b] = s;
    }
}

extern "C" void kernel_launch(void* const* d_in, const int* in_sizes, int n_in,
                              void* d_out, int out_size, void* d_ws, size_t ws_size,
                              hipStream_t stream)
{
    const float* x     = (const float*)d_in[0];
    const float* Wih0f = (const float*)d_in[1];
    const float* Whh0f = (const float*)d_in[2];
    const float* bih0f = (const float*)d_in[3];
    const float* bhh0f = (const float*)d_in[4];
    const float* Wih0r = (const float*)d_in[5];
    const float* Whh0r = (const float*)d_in[6];
    const float* bih0r = (const float*)d_in[7];
    const float* bhh0r = (const float*)d_in[8];
    const float* Wih1f = (const float*)d_in[9];
    const float* Whh1f = (const float*)d_in[10];
    const float* bih1f = (const float*)d_in[11];
    const float* bhh1f = (const float*)d_in[12];
    const float* Wih1r = (const float*)d_in[13];
    const float* bih1r = (const float*)d_in[15];
    const float* bhh1r = (const float*)d_in[16];
    const float* fcW   = (const float*)d_in[17];
    const float* fcb   = (const float*)d_in[18];

    const size_t need = (size_t)BB * TT * Hn * sizeof(float);   // 151 MB
    if (d_ws != nullptr && ws_size >= need) {
        float* h0r = (float*)d_ws;
        l0rev_kernel<<<BB / CH0, NT0, 0, stream>>>(x, Wih0r, Whh0r, bih0r, bhh0r, h0r);
        fused_fwd_kernel<<<BB / CH1, NT1, 0, stream>>>(
            x, Wih0f, Whh0f, bih0f, bhh0f, Wih1f, Whh1f, bih1f, bhh1f,
            Wih1r, bih1r, bhh1r, fcW, fcb, h0r, (float*)d_out);
    } else {
        fused_all_kernel<<<BB, G4, 0, stream>>>(
            x, Wih0f, Whh0f, bih0f, bhh0f, Wih0r, Whh0r, bih0r, bhh0r,
            Wih1f, Whh1f, bih1f, bhh1f, Wih1r, bih1r, bhh1r, fcW, fcb,
            (float*)d_out);
    }
}

// Round 3
// 3769.475 us; speedup vs baseline: 1.0023x; 1.0023x over previous
//
#include <hip/hip_runtime.h>
#include <cstdint>

#define Hn 36
#define G4 144          // 4*H gate rows
#define TT 512
#define BB 2048

__device__ __forceinline__ float sigf(float x) { return 1.0f / (1.0f + __expf(-x)); }
__device__ __forceinline__ float tanh_fast(float x) {
    float e = __expf(2.0f * x);          // exact +-1 limits via over/underflow
    return 1.0f - 2.0f / (e + 1.0f);
}

// dot products: W is a register array (constant indices only!), H is an LDS
// pointer read wave-uniformly (float4 broadcast, conflict-free).
#define DOT36(W, H, Z0, Z1, Z2, Z3)                        \
    do {                                                   \
        _Pragma("unroll") for (int _k = 0; _k < 9; ++_k) { \
            float4 hv = *(const float4*)&(H)[_k * 4];      \
            Z0 = fmaf((W)[_k * 4 + 0], hv.x, Z0);          \
            Z1 = fmaf((W)[_k * 4 + 1], hv.y, Z1);          \
            Z2 = fmaf((W)[_k * 4 + 2], hv.z, Z2);          \
            Z3 = fmaf((W)[_k * 4 + 3], hv.w, Z3);          \
        }                                                  \
    } while (0)

#define DOT72(W, H, Z0, Z1, Z2, Z3)                         \
    do {                                                    \
        _Pragma("unroll") for (int _k = 0; _k < 18; ++_k) { \
            float4 hv = *(const float4*)&(H)[_k * 4];       \
            Z0 = fmaf((W)[_k * 4 + 0], hv.x, Z0);           \
            Z1 = fmaf((W)[_k * 4 + 1], hv.y, Z1);           \
            Z2 = fmaf((W)[_k * 4 + 2], hv.z, Z2);           \
            Z3 = fmaf((W)[_k * 4 + 3], hv.w, Z3);           \
        }                                                   \
    } while (0)

// ======================= PRIMARY PATH (needs 151 MB ws) ======================
// Kernel 1: layer-0 reverse scan -> h0r (B, T, 36) fp32 in workspace.
#define CH0 4
#define NT0 (CH0 * G4)   // 576
__global__ __launch_bounds__(NT0, 1) void l0rev_kernel(
    const float* __restrict__ x,
    const float* __restrict__ Wih, const float* __restrict__ Whh,
    const float* __restrict__ bih, const float* __restrict__ bhh,
    float* __restrict__ h0r)
{
    const int tid = threadIdx.x;
    const int cc  = tid / G4;
    const int g   = tid % G4;
    const int b   = blockIdx.x * CH0 + cc;

    __shared__ float xs[CH0][TT];
    __shared__ float hs[CH0][40];
    __shared__ float zs[CH0][G4];

    for (int i = g; i < TT; i += G4) xs[cc][i] = x[(size_t)b * TT + i];

    float w[Hn];
#pragma unroll
    for (int k = 0; k < Hn; ++k) w[k] = Whh[g * Hn + k];
    const float wx   = Wih[g];
    const float bias = bih[g] + bhh[g];

    if (g < Hn) hs[cc][g] = 0.0f;
    float c = 0.0f;
    __syncthreads();

    float* rrow = h0r + (size_t)b * TT * Hn;
    for (int s = 0; s < TT; ++s) {
        const int t = TT - 1 - s;
        float z0 = fmaf(xs[cc][t], wx, bias), z1 = 0.f, z2 = 0.f, z3 = 0.f;
        DOT36(w, hs[cc], z0, z1, z2, z3);
        zs[cc][g] = (z0 + z1) + (z2 + z3);
        __syncthreads();
        if (g < Hn) {
            float zi = zs[cc][g], zf = zs[cc][g + 36], zg = zs[cc][g + 72], zo = zs[cc][g + 108];
            c = sigf(zf) * c + sigf(zi) * tanh_fast(zg);
            float h = sigf(zo) * tanh_fast(c);
            hs[cc][g] = h;
            rrow[(size_t)t * Hn + g] = h;
        }
        __syncthreads();
    }
}

// Kernel 2: fused L0-forward + L1-forward scan + single-step L1-reverse + FC.
#define CH1 2
#define NT1 (CH1 * G4)   // 288
__global__ __launch_bounds__(NT1, 1) void fused_fwd_kernel(
    const float* __restrict__ x,
    const float* __restrict__ Wih0f, const float* __restrict__ Whh0f,
    const float* __restrict__ bih0f, const float* __restrict__ bhh0f,
    const float* __restrict__ Wih1f, const float* __restrict__ Whh1f,
    const float* __restrict__ bih1f, const float* __restrict__ bhh1f,
    const float* __restrict__ Wih1r,
    const float* __restrict__ bih1r, const float* __restrict__ bhh1r,
    const float* __restrict__ fcW, const float* __restrict__ fcb,
    const float* __restrict__ h0r,
    float* __restrict__ out)
{
    const int tid = threadIdx.x;
    const int cc  = tid / G4;
    const int g   = tid % G4;
    const int b   = blockIdx.x * CH1 + cc;

    __shared__ float xs[CH1][TT];
    __shared__ float h0s[CH1][80];   // [h0f(36) | h0r(36)] = h0cat row
    __shared__ float hs1[CH1][40];
    __shared__ float zs[CH1][G4];
    __shared__ float red[CH1][40];

    for (int i = g; i < TT; i += G4) xs[cc][i] = x[(size_t)b * TT + i];

    float w0[Hn];
#pragma unroll
    for (int k = 0; k < Hn; ++k) w0[k] = Whh0f[g * Hn + k];
    const float wx0 = Wih0f[g];
    const float b0  = bih0f[g] + bhh0f[g];

    float w1i[72];
#pragma unroll
    for (int k = 0; k < 72; ++k) w1i[k] = Wih1f[g * 72 + k];
    float w1h[Hn];
#pragma unroll
    for (int k = 0; k < Hn; ++k) w1h[k] = Whh1f[g * Hn + k];
    const float b1 = bih1f[g] + bhh1f[g];

    if (g < Hn) { h0s[cc][g] = 0.0f; hs1[cc][g] = 0.0f; }
    float c0 = 0.0f, c1 = 0.0f;

    const float* rrow = h0r + (size_t)b * TT * Hn;
    float rv = (g >= 36 && g < 72) ? rrow[g - 36] : 0.0f;   // h0r(t=0)
    __syncthreads();

    for (int t = 0; t < TT; ++t) {
        // ---- phase A: layer-0 forward step ----
        float z0 = fmaf(xs[cc][t], wx0, b0), z1 = 0.f, z2 = 0.f, z3 = 0.f;
        DOT36(w0, h0s[cc], z0, z1, z2, z3);
        zs[cc][g] = (z0 + z1) + (z2 + z3);
        __syncthreads();
        if (g < Hn) {
            float zi = zs[cc][g], zf = zs[cc][g + 36], zg = zs[cc][g + 72], zo = zs[cc][g + 108];
            c0 = sigf(zf) * c0 + sigf(zi) * tanh_fast(zg);
            h0s[cc][g] = sigf(zo) * tanh_fast(c0);
        } else if (g < 72) {
            h0s[cc][g] = rv;                     // h0r(t), prefetched
        }
        __syncthreads();
        if (g >= 36 && g < 72 && t + 1 < TT)     // prefetch h0r(t+1)
            rv = rrow[(size_t)(t + 1) * Hn + (g - 36)];

        // ---- phase B: layer-1 forward step ----
        float y0 = b1, y1 = 0.f, y2 = 0.f, y3 = 0.f;
        DOT72(w1i, h0s[cc], y0, y1, y2, y3);
        DOT36(w1h, hs1[cc], y0, y1, y2, y3);
        zs[cc][g] = (y0 + y1) + (y2 + y3);
        __syncthreads();
        if (g < Hn) {
            float zi = zs[cc][g], zf = zs[cc][g + 36], zg = zs[cc][g + 72], zo = zs[cc][g + 108];
            c1 = sigf(zf) * c1 + sigf(zi) * tanh_fast(zg);
            hs1[cc][g] = sigf(zo) * tanh_fast(c1);
        }
        __syncthreads();
    }

    // ---- tail: L1 reverse single step at t=T-1 (h0=c0=0) + FC ----
    float zR = bih1r[g] + bhh1r[g];
#pragma unroll
    for (int k = 0; k < 72; ++k) zR = fmaf(Wih1r[g * 72 + k], h0s[cc][k], zR);
    zs[cc][g] = zR;
    __syncthreads();
    if (g < Hn) {
        float zi = zs[cc][g], zg = zs[cc][g + 72], zo = zs[cc][g + 108];
        float c  = sigf(zi) * tanh_fast(zg);     // c0=0: forget term vanishes
        float hr = sigf(zo) * tanh_fast(c);
        red[cc][g] = fcW[36 + g] * hr + fcW[g] * hs1[cc][g];
    }
    __syncthreads();
    if (g == 0) {
        float s = fcb[0];
        for (int j = 0; j < Hn; ++j) s += red[cc][j];
        out[b] = s;
    }
}

// ================= FALLBACK PATH (zero workspace, ckpt/recompute) ============
__global__ __launch_bounds__(G4, 1) void fused_all_kernel(
    const float* __restrict__ x,
    const float* __restrict__ Wih0f, const float* __restrict__ Whh0f,
    const float* __restrict__ bih0f, const float* __restrict__ bhh0f,
    const float* __restrict__ Wih0r, const float* __restrict__ Whh0r,
    const float* __restrict__ bih0r, const float* __restrict__ bhh0r,
    const float* __restrict__ Wih1f, const float* __restrict__ Whh1f,
    const float* __restrict__ bih1f, const float* __restrict__ bhh1f,
    const float* __restrict__ Wih1r,
    const float* __restrict__ bih1r, const float* __restrict__ bhh1r,
    const float* __restrict__ fcW, const float* __restrict__ fcb,
    float* __restrict__ out)
{
    const int g = threadIdx.x;
    const int b = blockIdx.x;

    __shared__ float xs[TT];
    __shared__ float cbuf[64][Hn];        // one 64-step chunk of h0r
    __shared__ float ckpt_h[8][Hn], ckpt_c[8][Hn];
    __shared__ float hr[40], h0s[80], hs1[40], zs[G4], red[40];

    for (int i = g; i < TT; i += G4) xs[i] = x[(size_t)b * TT + i];

    float wr[Hn], wf[Hn];
#pragma unroll
    for (int k = 0; k < Hn; ++k) wr[k] = Whh0r[g * Hn + k];
#pragma unroll
    for (int k = 0; k < Hn; ++k) wf[k] = Whh0f[g * Hn + k];
    const float wxr = Wih0r[g], br = bih0r[g] + bhh0r[g];
    const float wxf = Wih0f[g], bf = bih0f[g] + bhh0f[g];
    float w1i[72];
#pragma unroll
    for (int k = 0; k < 72; ++k) w1i[k] = Wih1f[g * 72 + k];
    float w1h[Hn];
#pragma unroll
    for (int k = 0; k < Hn; ++k) w1h[k] = Whh1f[g * Hn + k];
    const float b1 = bih1f[g] + bhh1f[g];

    // ---- pass 1: full reverse scan, saving (h,c) checkpoints ----
    if (g < Hn) hr[g] = 0.0f;
    float cr = 0.0f;
    __syncthreads();
    for (int s = 0; s < TT; ++s) {
        const int t = TT - 1 - s;
        if ((t & 63) == 63 && g < Hn) { ckpt_h[t >> 6][g] = hr[g]; ckpt_c[t >> 6][g] = cr; }
        float z0 = fmaf(xs[t], wxr, br), z1 = 0.f, z2 = 0.f, z3 = 0.f;
        DOT36(wr, hr, z0, z1, z2, z3);
        zs[g] = (z0 + z1) + (z2 + z3);
        __syncthreads();
        if (g < Hn) {
            float zi = zs[g], zf = zs[g + 36], zg = zs[g + 72], zo = zs[g + 108];
            cr = sigf(zf) * cr + sigf(zi) * tanh_fast(zg);
            hr[g] = sigf(zo) * tanh_fast(cr);
        }
        __syncthreads();
    }

    // ---- pass 2: per chunk, recompute reverse then run fused forward ----
    if (g < Hn) { h0s[g] = 0.0f; hs1[g] = 0.0f; }
    float c0 = 0.0f, c1 = 0.0f;
    __syncthreads();

    for (int m = 0; m < 8; ++m) {
        if (g < Hn) { hr[g] = ckpt_h[m][g]; cr = ckpt_c[m][g]; }
        __syncthreads();
        for (int j = 0; j < 64; ++j) {
            const int t = m * 64 + 63 - j;
            float z0 = fmaf(xs[t], wxr, br), z1 = 0.f, z2 = 0.f, z3 = 0.f;
            DOT36(wr, hr, z0, z1, z2, z3);
            zs[g] = (z0 + z1) + (z2 + z3);
            __syncthreads();
            if (g < Hn) {
                float zi = zs[g], zf = zs[g + 36], zg = zs[g + 72], zo = zs[g + 108];
                cr = sigf(zf) * cr + sigf(zi) * tanh_fast(zg);
                float h = sigf(zo) * tanh_fast(cr);
                hr[g] = h;
                cbuf[t & 63][g] = h;
            }
            __syncthreads();
        }
        for (int j = 0; j < 64; ++j) {
            const int t = m * 64 + j;
            float z0 = fmaf(xs[t], wxf, bf), z1 = 0.f, z2 = 0.f, z3 = 0.f;
            DOT36(wf, h0s, z0, z1, z2, z3);
            zs[g] = (z0 + z1) + (z2 + z3);
            __syncthreads();
            if (g < Hn) {
                float zi = zs[g], zf = zs[g + 36], zg = zs[g + 72], zo = zs[g + 108];
                c0 = sigf(zf) * c0 + sigf(zi) * tanh_fast(zg);
                h0s[g] = sigf(zo) * tanh_fast(c0);
            } else if (g < 72) {
                h0s[g] = cbuf[j][g - 36];
            }
            __syncthreads();
            float y0 = b1, y1 = 0.f, y2 = 0.f, y3 = 0.f;
            DOT72(w1i, h0s, y0, y1, y2, y3);
            DOT36(w1h, hs1, y0, y1, y2, y3);
            zs[g] = (y0 + y1) + (y2 + y3);
            __syncthreads();
            if (g < Hn) {
                float zi = zs[g], zf = zs[g + 36], zg = zs[g + 72], zo = zs[g + 108];
                c1 = sigf(zf) * c1 + sigf(zi) * tanh_fast(zg);
                hs1[g] = sigf(zo) * tanh_fast(c1);
            }
            __syncthreads();
        }
    }

    // ---- tail ----
    float zR = bih1r[g] + bhh1r[g];
#pragma unroll
    for (int k = 0; k < 72; ++k) zR = fmaf(Wih1r[g * 72 + k], h0s[k], zR);
    zs[g] = zR;
    __syncthreads();
    if (g < Hn) {
        float zi = zs[g], zg = zs[g + 72], zo = zs[g + 108];
        float c  = sigf(zi) * tanh_fast(zg);
        float hrv = sigf(zo) * tanh_fast(c);
        red[g] = fcW[36 + g] * hrv + fcW[g] * hs1[g];
    }
    __syncthreads();
    if (g == 0) {
        float s = fcb[0];
        for (int j = 0; j < Hn; ++j) s += red[j];
        out[b] = s;
    }
}

extern "C" void kernel_launch(void* const* d_in, const int* in_sizes, int n_in,
                              void* d_out, int out_size, void* d_ws, size_t ws_size,
                              hipStream_t stream)
{
    const float* x     = (const float*)d_in[0];
    const float* Wih0f = (const float*)d_in[1];
    const float* Whh0f = (const float*)d_in[2];
    const float* bih0f = (const float*)d_in[3];
    const float* bhh0f = (const float*)d_in[4];
    const float* Wih0r = (const float*)d_in[5];
    const float* Whh0r = (const float*)d_in[6];
    const float* bih0r = (const float*)d_in[7];
    const float* bhh0r = (const float*)d_in[8];
    const float* Wih1f = (const float*)d_in[9];
    const float* Whh1f = (const float*)d_in[10];
    const float* bih1f = (const float*)d_in[11];
    const float* bhh1f = (const float*)d_in[12];
    const float* Wih1r = (const float*)d_in[13];
    const float* bih1r = (const float*)d_in[15];
    const float* bhh1r = (const float*)d_in[16];
    const float* fcW   = (const float*)d_in[17];
    const float* fcb   = (const float*)d_in[18];

    const size_t need = (size_t)BB * TT * Hn * sizeof(float);   // 151 MB
    if (d_ws != nullptr && ws_size >= need) {
        float* h0r = (float*)d_ws;
        l0rev_kernel<<<BB / CH0, NT0, 0, stream>>>(x, Wih0r, Whh0r, bih0r, bhh0r, h0r);
        fused_fwd_kernel<<<BB / CH1, NT1, 0, stream>>>(
            x, Wih0f, Whh0f, bih0f, bhh0f, Wih1f, Whh1f, bih1f, bhh1f,
            Wih1r, bih1r, bhh1r, fcW, fcb, h0r, (float*)d_out);
    } else {
        fused_all_kernel<<<BB, G4, 0, stream>>>(
            x, Wih0f, Whh0f, bih0f, bhh0f, Wih0r, Whh0r, bih0r, bhh0r,
            Wih1f, Whh1f, bih1f, bhh1f, Wih1r, bih1r, bhh1r, fcW, fcb,
            (float*)d_out);
    }
}

// Round 4
// 3711.265 us; speedup vs baseline: 1.0180x; 1.0157x over previous
//
#include <hip/hip_runtime.h>
#include <cstdint>

#define Hn 36
#define G4 144          // 4*H gate rows
#define TT 512
#define BB 2048

__device__ __forceinline__ float sigf(float x) { return 1.0f / (1.0f + __expf(-x)); }
__device__ __forceinline__ float tanh_fast(float x) {
    float e = __expf(2.0f * x);          // exact +-1 limits via over/underflow
    return 1.0f - 2.0f / (e + 1.0f);
}

// Force-materialize a register array: the empty asm "writes" each element, so
// LLVM cannot re-load it from memory inside the loop (defeats load sinking).
#define PIN(arr, n)                                              \
    do {                                                         \
        _Pragma("unroll") for (int _p = 0; _p < (n); ++_p)       \
            asm volatile("" : "+v"((arr)[_p]));                  \
    } while (0)

// dot products: W is a register array (constant indices only!), H is an LDS
// pointer read wave-uniformly (float4 broadcast, conflict-free).
#define DOT36(W, H, Z0, Z1, Z2, Z3)                        \
    do {                                                   \
        _Pragma("unroll") for (int _k = 0; _k < 9; ++_k) { \
            float4 hv = *(const float4*)&(H)[_k * 4];      \
            Z0 = fmaf((W)[_k * 4 + 0], hv.x, Z0);          \
            Z1 = fmaf((W)[_k * 4 + 1], hv.y, Z1);          \
            Z2 = fmaf((W)[_k * 4 + 2], hv.z, Z2);          \
            Z3 = fmaf((W)[_k * 4 + 3], hv.w, Z3);          \
        }                                                  \
    } while (0)

#define DOT72(W, H, Z0, Z1, Z2, Z3)                         \
    do {                                                    \
        _Pragma("unroll") for (int _k = 0; _k < 18; ++_k) { \
            float4 hv = *(const float4*)&(H)[_k * 4];       \
            Z0 = fmaf((W)[_k * 4 + 0], hv.x, Z0);           \
            Z1 = fmaf((W)[_k * 4 + 1], hv.y, Z1);           \
            Z2 = fmaf((W)[_k * 4 + 2], hv.z, Z2);           \
            Z3 = fmaf((W)[_k * 4 + 3], hv.w, Z3);           \
        }                                                   \
    } while (0)

// ======================= PRIMARY PATH (needs 151 MB ws) ======================
// Kernel 1: layer-0 reverse scan -> h0r (B, T, 36) fp32 in workspace.
#define CH0 4
#define NT0 (CH0 * G4)   // 576
__global__ __launch_bounds__(NT0, 1) void l0rev_kernel(
    const float* __restrict__ x,
    const float* __restrict__ Wih, const float* __restrict__ Whh,
    const float* __restrict__ bih, const float* __restrict__ bhh,
    float* __restrict__ h0r)
{
    const int tid = threadIdx.x;
    const int cc  = tid / G4;
    const int g   = tid % G4;
    const int b   = blockIdx.x * CH0 + cc;

    __shared__ float xs[CH0][TT];
    __shared__ float hs[CH0][40];
    __shared__ float zs[CH0][G4];

    for (int i = g; i < TT; i += G4) xs[cc][i] = x[(size_t)b * TT + i];

    float w[Hn];
#pragma unroll
    for (int k = 0; k < Hn; ++k) w[k] = Whh[g * Hn + k];
    const float wx   = Wih[g];
    const float bias = bih[g] + bhh[g];
    PIN(w, Hn);

    if (g < Hn) hs[cc][g] = 0.0f;
    float c = 0.0f;
    __syncthreads();

    float* rrow = h0r + (size_t)b * TT * Hn;
    for (int s = 0; s < TT; ++s) {
        const int t = TT - 1 - s;
        float z0 = fmaf(xs[cc][t], wx, bias), z1 = 0.f, z2 = 0.f, z3 = 0.f;
        DOT36(w, hs[cc], z0, z1, z2, z3);
        zs[cc][g] = (z0 + z1) + (z2 + z3);
        __syncthreads();
        if (g < Hn) {
            float zi = zs[cc][g], zf = zs[cc][g + 36], zg = zs[cc][g + 72], zo = zs[cc][g + 108];
            c = sigf(zf) * c + sigf(zi) * tanh_fast(zg);
            float h = sigf(zo) * tanh_fast(c);
            hs[cc][g] = h;
            rrow[(size_t)t * Hn + g] = h;
        }
        __syncthreads();
    }
}

// Kernel 2: fused L0-forward + L1-forward scan + single-step L1-reverse + FC.
#define CH1 2
#define NT1 (CH1 * G4)   // 288
__global__ __launch_bounds__(NT1, 1) void fused_fwd_kernel(
    const float* __restrict__ x,
    const float* __restrict__ Wih0f, const float* __restrict__ Whh0f,
    const float* __restrict__ bih0f, const float* __restrict__ bhh0f,
    const float* __restrict__ Wih1f, const float* __restrict__ Whh1f,
    const float* __restrict__ bih1f, const float* __restrict__ bhh1f,
    const float* __restrict__ Wih1r,
    const float* __restrict__ bih1r, const float* __restrict__ bhh1r,
    const float* __restrict__ fcW, const float* __restrict__ fcb,
    const float* __restrict__ h0r,
    float* __restrict__ out)
{
    const int tid = threadIdx.x;
    const int cc  = tid / G4;
    const int g   = tid % G4;
    const int b   = blockIdx.x * CH1 + cc;

    __shared__ float xs[CH1][TT];
    __shared__ float h0s[CH1][80];   // [h0f(36) | h0r(36)] = h0cat row
    __shared__ float hs1[CH1][40];
    __shared__ float zs[CH1][G4];
    __shared__ float red[CH1][40];

    for (int i = g; i < TT; i += G4) xs[cc][i] = x[(size_t)b * TT + i];

    float w0[Hn];
#pragma unroll
    for (int k = 0; k < Hn; ++k) w0[k] = Whh0f[g * Hn + k];
    const float wx0 = Wih0f[g];
    const float b0  = bih0f[g] + bhh0f[g];

    float w1i[72];
#pragma unroll
    for (int k = 0; k < 72; ++k) w1i[k] = Wih1f[g * 72 + k];
    float w1h[Hn];
#pragma unroll
    for (int k = 0; k < Hn; ++k) w1h[k] = Whh1f[g * Hn + k];
    const float b1 = bih1f[g] + bhh1f[g];

    PIN(w0, Hn);
    PIN(w1i, 72);
    PIN(w1h, Hn);

    if (g < Hn) { h0s[cc][g] = 0.0f; hs1[cc][g] = 0.0f; }
    float c0 = 0.0f, c1 = 0.0f;

    const float* rrow = h0r + (size_t)b * TT * Hn;
    float rv = (g >= 36 && g < 72) ? rrow[g - 36] : 0.0f;   // h0r(t=0)
    __syncthreads();

    for (int t = 0; t < TT; ++t) {
        // ---- phase A: layer-0 forward step ----
        float z0 = fmaf(xs[cc][t], wx0, b0), z1 = 0.f, z2 = 0.f, z3 = 0.f;
        DOT36(w0, h0s[cc], z0, z1, z2, z3);
        zs[cc][g] = (z0 + z1) + (z2 + z3);
        __syncthreads();
        if (g < Hn) {
            float zi = zs[cc][g], zf = zs[cc][g + 36], zg = zs[cc][g + 72], zo = zs[cc][g + 108];
            c0 = sigf(zf) * c0 + sigf(zi) * tanh_fast(zg);
            h0s[cc][g] = sigf(zo) * tanh_fast(c0);
        } else if (g < 72) {
            h0s[cc][g] = rv;                     // h0r(t), prefetched
        }
        __syncthreads();
        if (g >= 36 && g < 72 && t + 1 < TT)     // prefetch h0r(t+1)
            rv = rrow[(size_t)(t + 1) * Hn + (g - 36)];

        // ---- phase B: layer-1 forward step ----
        float y0 = b1, y1 = 0.f, y2 = 0.f, y3 = 0.f;
        DOT72(w1i, h0s[cc], y0, y1, y2, y3);
        DOT36(w1h, hs1[cc], y0, y1, y2, y3);
        zs[cc][g] = (y0 + y1) + (y2 + y3);
        __syncthreads();
        if (g < Hn) {
            float zi = zs[cc][g], zf = zs[cc][g + 36], zg = zs[cc][g + 72], zo = zs[cc][g + 108];
            c1 = sigf(zf) * c1 + sigf(zi) * tanh_fast(zg);
            hs1[cc][g] = sigf(zo) * tanh_fast(c1);
        }
        __syncthreads();
    }

    // ---- tail: L1 reverse single step at t=T-1 (h0=c0=0) + FC ----
    float zR = bih1r[g] + bhh1r[g];
#pragma unroll
    for (int k = 0; k < 72; ++k) zR = fmaf(Wih1r[g * 72 + k], h0s[cc][k], zR);
    zs[cc][g] = zR;
    __syncthreads();
    if (g < Hn) {
        float zi = zs[cc][g], zg = zs[cc][g + 72], zo = zs[cc][g + 108];
        float c  = sigf(zi) * tanh_fast(zg);     // c0=0: forget term vanishes
        float hr = sigf(zo) * tanh_fast(c);
        red[cc][g] = fcW[36 + g] * hr + fcW[g] * hs1[cc][g];
    }
    __syncthreads();
    if (g == 0) {
        float s = fcb[0];
        for (int j = 0; j < Hn; ++j) s += red[cc][j];
        out[b] = s;
    }
}

// ================= FALLBACK PATH (zero workspace, ckpt/recompute) ============
__global__ __launch_bounds__(G4, 1) void fused_all_kernel(
    const float* __restrict__ x,
    const float* __restrict__ Wih0f, const float* __restrict__ Whh0f,
    const float* __restrict__ bih0f, const float* __restrict__ bhh0f,
    const float* __restrict__ Wih0r, const float* __restrict__ Whh0r,
    const float* __restrict__ bih0r, const float* __restrict__ bhh0r,
    const float* __restrict__ Wih1f, const float* __restrict__ Whh1f,
    const float* __restrict__ bih1f, const float* __restrict__ bhh1f,
    const float* __restrict__ Wih1r,
    const float* __restrict__ bih1r, const float* __restrict__ bhh1r,
    const float* __restrict__ fcW, const float* __restrict__ fcb,
    float* __restrict__ out)
{
    const int g = threadIdx.x;
    const int b = blockIdx.x;

    __shared__ float xs[TT];
    __shared__ float cbuf[64][Hn];        // one 64-step chunk of h0r
    __shared__ float ckpt_h[8][Hn], ckpt_c[8][Hn];
    __shared__ float hr[40], h0s[80], hs1[40], zs[G4], red[40];

    for (int i = g; i < TT; i += G4) xs[i] = x[(size_t)b * TT + i];

    float wr[Hn], wf[Hn];
#pragma unroll
    for (int k = 0; k < Hn; ++k) wr[k] = Whh0r[g * Hn + k];
#pragma unroll
    for (int k = 0; k < Hn; ++k) wf[k] = Whh0f[g * Hn + k];
    const float wxr = Wih0r[g], br = bih0r[g] + bhh0r[g];
    const float wxf = Wih0f[g], bf = bih0f[g] + bhh0f[g];
    float w1i[72];
#pragma unroll
    for (int k = 0; k < 72; ++k) w1i[k] = Wih1f[g * 72 + k];
    float w1h[Hn];
#pragma unroll
    for (int k = 0; k < Hn; ++k) w1h[k] = Whh1f[g * Hn + k];
    const float b1 = bih1f[g] + bhh1f[g];
    PIN(wr, Hn);
    PIN(wf, Hn);
    PIN(w1i, 72);
    PIN(w1h, Hn);

    // ---- pass 1: full reverse scan, saving (h,c) checkpoints ----
    if (g < Hn) hr[g] = 0.0f;
    float cr = 0.0f;
    __syncthreads();
    for (int s = 0; s < TT; ++s) {
        const int t = TT - 1 - s;
        if ((t & 63) == 63 && g < Hn) { ckpt_h[t >> 6][g] = hr[g]; ckpt_c[t >> 6][g] = cr; }
        float z0 = fmaf(xs[t], wxr, br), z1 = 0.f, z2 = 0.f, z3 = 0.f;
        DOT36(wr, hr, z0, z1, z2, z3);
        zs[g] = (z0 + z1) + (z2 + z3);
        __syncthreads();
        if (g < Hn) {
            float zi = zs[g], zf = zs[g + 36], zg = zs[g + 72], zo = zs[g + 108];
            cr = sigf(zf) * cr + sigf(zi) * tanh_fast(zg);
            hr[g] = sigf(zo) * tanh_fast(cr);
        }
        __syncthreads();
    }

    // ---- pass 2: per chunk, recompute reverse then run fused forward ----
    if (g < Hn) { h0s[g] = 0.0f; hs1[g] = 0.0f; }
    float c0 = 0.0f, c1 = 0.0f;
    __syncthreads();

    for (int m = 0; m < 8; ++m) {
        if (g < Hn) { hr[g] = ckpt_h[m][g]; cr = ckpt_c[m][g]; }
        __syncthreads();
        for (int j = 0; j < 64; ++j) {
            const int t = m * 64 + 63 - j;
            float z0 = fmaf(xs[t], wxr, br), z1 = 0.f, z2 = 0.f, z3 = 0.f;
            DOT36(wr, hr, z0, z1, z2, z3);
            zs[g] = (z0 + z1) + (z2 + z3);
            __syncthreads();
            if (g < Hn) {
                float zi = zs[g], zf = zs[g + 36], zg = zs[g + 72], zo = zs[g + 108];
                cr = sigf(zf) * cr + sigf(zi) * tanh_fast(zg);
                float h = sigf(zo) * tanh_fast(cr);
                hr[g] = h;
                cbuf[t & 63][g] = h;
            }
            __syncthreads();
        }
        for (int j = 0; j < 64; ++j) {
            const int t = m * 64 + j;
            float z0 = fmaf(xs[t], wxf, bf), z1 = 0.f, z2 = 0.f, z3 = 0.f;
            DOT36(wf, h0s, z0, z1, z2, z3);
            zs[g] = (z0 + z1) + (z2 + z3);
            __syncthreads();
            if (g < Hn) {
                float zi = zs[g], zf = zs[g + 36], zg = zs[g + 72], zo = zs[g + 108];
                c0 = sigf(zf) * c0 + sigf(zi) * tanh_fast(zg);
                h0s[g] = sigf(zo) * tanh_fast(c0);
            } else if (g < 72) {
                h0s[g] = cbuf[j][g - 36];
            }
            __syncthreads();
            float y0 = b1, y1 = 0.f, y2 = 0.f, y3 = 0.f;
            DOT72(w1i, h0s, y0, y1, y2, y3);
            DOT36(w1h, hs1, y0, y1, y2, y3);
            zs[g] = (y0 + y1) + (y2 + y3);
            __syncthreads();
            if (g < Hn) {
                float zi = zs[g], zf = zs[g + 36], zg = zs[g + 72], zo = zs[g + 108];
                c1 = sigf(zf) * c1 + sigf(zi) * tanh_fast(zg);
                hs1[g] = sigf(zo) * tanh_fast(c1);
            }
            __syncthreads();
        }
    }

    // ---- tail ----
    float zR = bih1r[g] + bhh1r[g];
#pragma unroll
    for (int k = 0; k < 72; ++k) zR = fmaf(Wih1r[g * 72 + k], h0s[k], zR);
    zs[g] = zR;
    __syncthreads();
    if (g < Hn) {
        float zi = zs[g], zg = zs[g + 72], zo = zs[g + 108];
        float c  = sigf(zi) * tanh_fast(zg);
        float hrv = sigf(zo) * tanh_fast(c);
        red[g] = fcW[36 + g] * hrv + fcW[g] * hs1[g];
    }
    __syncthreads();
    if (g == 0) {
        float s = fcb[0];
        for (int j = 0; j < Hn; ++j) s += red[j];
        out[b] = s;
    }
}

extern "C" void kernel_launch(void* const* d_in, const int* in_sizes, int n_in,
                              void* d_out, int out_size, void* d_ws, size_t ws_size,
                              hipStream_t stream)
{
    const float* x     = (const float*)d_in[0];
    const float* Wih0f = (const float*)d_in[1];
    const float* Whh0f = (const float*)d_in[2];
    const float* bih0f = (const float*)d_in[3];
    const float* bhh0f = (const float*)d_in[4];
    const float* Wih0r = (const float*)d_in[5];
    const float* Whh0r = (const float*)d_in[6];
    const float* bih0r = (const float*)d_in[7];
    const float* bhh0r = (const float*)d_in[8];
    const float* Wih1f = (const float*)d_in[9];
    const float* Whh1f = (const float*)d_in[10];
    const float* bih1f = (const float*)d_in[11];
    const float* bhh1f = (const float*)d_in[12];
    const float* Wih1r = (const float*)d_in[13];
    const float* bih1r = (const float*)d_in[15];
    const float* bhh1r = (const float*)d_in[16];
    const float* fcW   = (const float*)d_in[17];
    const float* fcb   = (const float*)d_in[18];

    const size_t need = (size_t)BB * TT * Hn * sizeof(float);   // 151 MB
    if (d_ws != nullptr && ws_size >= need) {
        float* h0r = (float*)d_ws;
        l0rev_kernel<<<BB / CH0, NT0, 0, stream>>>(x, Wih0r, Whh0r, bih0r, bhh0r, h0r);
        fused_fwd_kernel<<<BB / CH1, NT1, 0, stream>>>(
            x, Wih0f, Whh0f, bih0f, bhh0f, Wih1f, Whh1f, bih1f, bhh1f,
            Wih1r, bih1r, bhh1r, fcW, fcb, h0r, (float*)d_out);
    } else {
        fused_all_kernel<<<BB, G4, 0, stream>>>(
            x, Wih0f, Whh0f, bih0f, bhh0f, Wih0r, Whh0r, bih0r, bhh0r,
            Wih1f, Whh1f, bih1f, bhh1f, Wih1r, bih1r, bhh1r, fcW, fcb,
            (float*)d_out);
    }
}

// Round 6
// 3710.841 us; speedup vs baseline: 1.0181x; 1.0001x over previous
//
#include <hip/hip_runtime.h>
#include <cstdint>

#define Hn 36
#define G4 144          // 4*H gate rows
#define TT 512
#define BB 2048

__device__ __forceinline__ float sigf(float x) { return 1.0f / (1.0f + __expf(-x)); }
__device__ __forceinline__ float tanh_fast(float x) {
    float e = __expf(2.0f * x);          // exact +-1 limits via over/underflow
    return 1.0f - 2.0f / (e + 1.0f);
}

// ---- named-register weight machinery: NO arrays -> nothing can go to scratch.
// Each "quad" is 4 named scalar floats (float4 asm ties are unsupported on
// gfx950; scalar "+v" ties compile fine).
#define REP9(M, P)  M(P,0) M(P,1) M(P,2) M(P,3) M(P,4) M(P,5) M(P,6) M(P,7) M(P,8)
#define REP18(M, P) REP9(M, P) M(P,9) M(P,10) M(P,11) M(P,12) M(P,13) M(P,14) M(P,15) M(P,16) M(P,17)

#define DECLW(P, i) float P##i##x, P##i##y, P##i##z, P##i##w;
#define LOADW(P, i) { float4 _t = wp[i]; P##i##x = _t.x; P##i##y = _t.y; P##i##z = _t.z; P##i##w = _t.w; }
#define PINW(P, i)  asm volatile("" : "+v"(P##i##x), "+v"(P##i##y), "+v"(P##i##z), "+v"(P##i##w));
// hb must be a local `const float*` into LDS; i is a literal -> all compile-time.
#define FMA4_(P, i)                                                       \
    {  float4 hv = *(const float4*)&hb[(i) * 4];                          \
       z0 = fmaf(P##i##x, hv.x, z0); z1 = fmaf(P##i##y, hv.y, z1);        \
       z2 = fmaf(P##i##z, hv.z, z2); z3 = fmaf(P##i##w, hv.w, z3); }

// array-based dots (fallback kernel only — unused when workspace is present)
#define DOT36(W, H, Z0, Z1, Z2, Z3)                        \
    do {                                                   \
        _Pragma("unroll") for (int _k = 0; _k < 9; ++_k) { \
            float4 hv = *(const float4*)&(H)[_k * 4];      \
            Z0 = fmaf((W)[_k * 4 + 0], hv.x, Z0);          \
            Z1 = fmaf((W)[_k * 4 + 1], hv.y, Z1);          \
            Z2 = fmaf((W)[_k * 4 + 2], hv.z, Z2);          \
            Z3 = fmaf((W)[_k * 4 + 3], hv.w, Z3);          \
        }                                                  \
    } while (0)

#define DOT72(W, H, Z0, Z1, Z2, Z3)                         \
    do {                                                    \
        _Pragma("unroll") for (int _k = 0; _k < 18; ++_k) { \
            float4 hv = *(const float4*)&(H)[_k * 4];       \
            Z0 = fmaf((W)[_k * 4 + 0], hv.x, Z0);           \
            Z1 = fmaf((W)[_k * 4 + 1], hv.y, Z1);           \
            Z2 = fmaf((W)[_k * 4 + 2], hv.z, Z2);           \
            Z3 = fmaf((W)[_k * 4 + 3], hv.w, Z3);           \
        }                                                   \
    } while (0)

// ======================= PRIMARY PATH (needs 151 MB ws) ======================
// Kernel 1: layer-0 reverse scan -> h0r (B, T, 36) fp32 in workspace.
#define CH0 4
#define NT0 (CH0 * G4)   // 576
__global__ __launch_bounds__(NT0, 1) void l0rev_kernel(
    const float* __restrict__ x,
    const float* __restrict__ Wih, const float* __restrict__ Whh,
    const float* __restrict__ bih, const float* __restrict__ bhh,
    float* __restrict__ h0r)
{
    const int tid = threadIdx.x;
    const int cc  = tid / G4;
    const int g   = tid % G4;
    const int b   = blockIdx.x * CH0 + cc;

    __shared__ float xs[CH0][TT];
    __shared__ float hs[CH0][40];
    __shared__ float zs[CH0][G4];

    for (int i = g; i < TT; i += G4) xs[cc][i] = x[(size_t)b * TT + i];

    REP9(DECLW, wR)
    {
        const float4* wp = (const float4*)(Whh + g * Hn);   // 144B rows, 16B-aligned
        REP9(LOADW, wR)
    }
    float wx   = Wih[g];
    float bias = bih[g] + bhh[g];
    REP9(PINW, wR)
    asm volatile("" : "+v"(wx), "+v"(bias));

    if (g < Hn) hs[cc][g] = 0.0f;
    float c = 0.0f;
    __syncthreads();

    float* rrow = h0r + (size_t)b * TT * Hn;
    for (int s = 0; s < TT; ++s) {
        const int t = TT - 1 - s;
        float z0 = fmaf(xs[cc][t], wx, bias), z1 = 0.f, z2 = 0.f, z3 = 0.f;
        {
            const float* hb = hs[cc];
            REP9(FMA4_, wR)
        }
        zs[cc][g] = (z0 + z1) + (z2 + z3);
        __syncthreads();
        if (g < Hn) {
            float zi = zs[cc][g], zf = zs[cc][g + 36], zg = zs[cc][g + 72], zo = zs[cc][g + 108];
            c = sigf(zf) * c + sigf(zi) * tanh_fast(zg);
            float h = sigf(zo) * tanh_fast(c);
            hs[cc][g] = h;
            rrow[(size_t)t * Hn + g] = h;
        }
        __syncthreads();
    }
}

// Kernel 2: fused L0-forward + L1-forward scan + single-step L1-reverse + FC.
#define CH1 2
#define NT1 (CH1 * G4)   // 288
__global__ __launch_bounds__(NT1, 1) void fused_fwd_kernel(
    const float* __restrict__ x,
    const float* __restrict__ Wih0f, const float* __restrict__ Whh0f,
    const float* __restrict__ bih0f, const float* __restrict__ bhh0f,
    const float* __restrict__ Wih1f, const float* __restrict__ Whh1f,
    const float* __restrict__ bih1f, const float* __restrict__ bhh1f,
    const float* __restrict__ Wih1r,
    const float* __restrict__ bih1r, const float* __restrict__ bhh1r,
    const float* __restrict__ fcW, const float* __restrict__ fcb,
    const float* __restrict__ h0r,
    float* __restrict__ out)
{
    const int tid = threadIdx.x;
    const int cc  = tid / G4;
    const int g   = tid % G4;
    const int b   = blockIdx.x * CH1 + cc;

    __shared__ float xs[CH1][TT];
    __shared__ float h0s[CH1][80];   // [h0f(36) | h0r(36)] = h0cat row
    __shared__ float hs1[CH1][40];
    __shared__ float zs[CH1][G4];
    __shared__ float red[CH1][40];

    for (int i = g; i < TT; i += G4) xs[cc][i] = x[(size_t)b * TT + i];

    // named-register weights: wA = Whh0f row (36), wI = Wih1f row (72), wH = Whh1f row (36)
    REP9(DECLW, wA)
    REP18(DECLW, wI)
    REP9(DECLW, wH)
    {
        const float4* wp = (const float4*)(Whh0f + g * Hn);
        REP9(LOADW, wA)
    }
    {
        const float4* wp = (const float4*)(Wih1f + g * 72);
        REP18(LOADW, wI)
    }
    {
        const float4* wp = (const float4*)(Whh1f + g * Hn);
        REP9(LOADW, wH)
    }
    float wx0 = Wih0f[g];
    float b0  = bih0f[g] + bhh0f[g];
    float b1  = bih1f[g] + bhh1f[g];
    REP9(PINW, wA)
    REP18(PINW, wI)
    REP9(PINW, wH)
    asm volatile("" : "+v"(wx0), "+v"(b0), "+v"(b1));

    if (g < Hn) { h0s[cc][g] = 0.0f; hs1[cc][g] = 0.0f; }
    float c0 = 0.0f, c1 = 0.0f;

    const float* rrow = h0r + (size_t)b * TT * Hn;
    float rv = (g >= 36 && g < 72) ? rrow[g - 36] : 0.0f;   // h0r(t=0)
    __syncthreads();

    for (int t = 0; t < TT; ++t) {
        // ---- phase A: layer-0 forward step ----
        float z0 = fmaf(xs[cc][t], wx0, b0), z1 = 0.f, z2 = 0.f, z3 = 0.f;
        {
            const float* hb = h0s[cc];
            REP9(FMA4_, wA)
        }
        zs[cc][g] = (z0 + z1) + (z2 + z3);
        __syncthreads();
        if (g < Hn) {
            float zi = zs[cc][g], zf = zs[cc][g + 36], zg = zs[cc][g + 72], zo = zs[cc][g + 108];
            c0 = sigf(zf) * c0 + sigf(zi) * tanh_fast(zg);
            h0s[cc][g] = sigf(zo) * tanh_fast(c0);
        } else if (g < 72) {
            h0s[cc][g] = rv;                     // h0r(t), prefetched
        }
        __syncthreads();
        if (g >= 36 && g < 72 && t + 1 < TT)     // prefetch h0r(t+1)
            rv = rrow[(size_t)(t + 1) * Hn + (g - 36)];

        // ---- phase B: layer-1 forward step ----
        {
            z0 = b1; z1 = 0.f; z2 = 0.f; z3 = 0.f;
            {
                const float* hb = h0s[cc];       // 72 floats = 18 float4
                REP18(FMA4_, wI)
            }
            {
                const float* hb = hs1[cc];       // 36 floats = 9 float4
                REP9(FMA4_, wH)
            }
        }
        zs[cc][g] = (z0 + z1) + (z2 + z3);
        __syncthreads();
        if (g < Hn) {
            float zi = zs[cc][g], zf = zs[cc][g + 36], zg = zs[cc][g + 72], zo = zs[cc][g + 108];
            c1 = sigf(zf) * c1 + sigf(zi) * tanh_fast(zg);
            hs1[cc][g] = sigf(zo) * tanh_fast(c1);
        }
        __syncthreads();
    }

    // ---- tail: L1 reverse single step at t=T-1 (h0=c0=0) + FC ----
    float zR = bih1r[g] + bhh1r[g];
#pragma unroll
    for (int k = 0; k < 72; ++k) zR = fmaf(Wih1r[g * 72 + k], h0s[cc][k], zR);
    zs[cc][g] = zR;
    __syncthreads();
    if (g < Hn) {
        float zi = zs[cc][g], zg = zs[cc][g + 72], zo = zs[cc][g + 108];
        float c  = sigf(zi) * tanh_fast(zg);     // c0=0: forget term vanishes
        float hr = sigf(zo) * tanh_fast(c);
        red[cc][g] = fcW[36 + g] * hr + fcW[g] * hs1[cc][g];
    }
    __syncthreads();
    if (g == 0) {
        float s = fcb[0];
        for (int j = 0; j < Hn; ++j) s += red[cc][j];
        out[b] = s;
    }
}

// ================= FALLBACK PATH (zero workspace, ckpt/recompute) ============
// Unused when the harness provides >=151MB workspace (it does today); kept for
// safety. Correctness-first, not perf-tuned.
__global__ __launch_bounds__(G4, 1) void fused_all_kernel(
    const float* __restrict__ x,
    const float* __restrict__ Wih0f, const float* __restrict__ Whh0f,
    const float* __restrict__ bih0f, const float* __restrict__ bhh0f,
    const float* __restrict__ Wih0r, const float* __restrict__ Whh0r,
    const float* __restrict__ bih0r, const float* __restrict__ bhh0r,
    const float* __restrict__ Wih1f, const float* __restrict__ Whh1f,
    const float* __restrict__ bih1f, const float* __restrict__ bhh1f,
    const float* __restrict__ Wih1r,
    const float* __restrict__ bih1r, const float* __restrict__ bhh1r,
    const float* __restrict__ fcW, const float* __restrict__ fcb,
    float* __restrict__ out)
{
    const int g = threadIdx.x;
    const int b = blockIdx.x;

    __shared__ float xs[TT];
    __shared__ float cbuf[64][Hn];        // one 64-step chunk of h0r
    __shared__ float ckpt_h[8][Hn], ckpt_c[8][Hn];
    __shared__ float hr[40], h0s[80], hs1[40], zs[G4], red[40];

    for (int i = g; i < TT; i += G4) xs[i] = x[(size_t)b * TT + i];

    float wr[Hn], wf[Hn];
#pragma unroll
    for (int k = 0; k < Hn; ++k) wr[k] = Whh0r[g * Hn + k];
#pragma unroll
    for (int k = 0; k < Hn; ++k) wf[k] = Whh0f[g * Hn + k];
    const float wxr = Wih0r[g], br = bih0r[g] + bhh0r[g];
    const float wxf = Wih0f[g], bf = bih0f[g] + bhh0f[g];
    float w1i[72];
#pragma unroll
    for (int k = 0; k < 72; ++k) w1i[k] = Wih1f[g * 72 + k];
    float w1h[Hn];
#pragma unroll
    for (int k = 0; k < Hn; ++k) w1h[k] = Whh1f[g * Hn + k];
    const float b1 = bih1f[g] + bhh1f[g];

    // ---- pass 1: full reverse scan, saving (h,c) checkpoints ----
    if (g < Hn) hr[g] = 0.0f;
    float cr = 0.0f;
    __syncthreads();
    for (int s = 0; s < TT; ++s) {
        const int t = TT - 1 - s;
        if ((t & 63) == 63 && g < Hn) { ckpt_h[t >> 6][g] = hr[g]; ckpt_c[t >> 6][g] = cr; }
        float z0 = fmaf(xs[t], wxr, br), z1 = 0.f, z2 = 0.f, z3 = 0.f;
        DOT36(wr, hr, z0, z1, z2, z3);
        zs[g] = (z0 + z1) + (z2 + z3);
        __syncthreads();
        if (g < Hn) {
            float zi = zs[g], zf = zs[g + 36], zg = zs[g + 72], zo = zs[g + 108];
            cr = sigf(zf) * cr + sigf(zi) * tanh_fast(zg);
            hr[g] = sigf(zo) * tanh_fast(cr);
        }
        __syncthreads();
    }

    // ---- pass 2: per chunk, recompute reverse then run fused forward ----
    if (g < Hn) { h0s[g] = 0.0f; hs1[g] = 0.0f; }
    float c0 = 0.0f, c1 = 0.0f;
    __syncthreads();

    for (int m = 0; m < 8; ++m) {
        if (g < Hn) { hr[g] = ckpt_h[m][g]; cr = ckpt_c[m][g]; }
        __syncthreads();
        for (int j = 0; j < 64; ++j) {
            const int t = m * 64 + 63 - j;
            float z0 = fmaf(xs[t], wxr, br), z1 = 0.f, z2 = 0.f, z3 = 0.f;
            DOT36(wr, hr, z0, z1, z2, z3);
            zs[g] = (z0 + z1) + (z2 + z3);
            __syncthreads();
            if (g < Hn) {
                float zi = zs[g], zf = zs[g + 36], zg = zs[g + 72], zo = zs[g + 108];
                cr = sigf(zf) * cr + sigf(zi) * tanh_fast(zg);
                float h = sigf(zo) * tanh_fast(cr);
                hr[g] = h;
                cbuf[t & 63][g] = h;
            }
            __syncthreads();
        }
        for (int j = 0; j < 64; ++j) {
            const int t = m * 64 + j;
            float z0 = fmaf(xs[t], wxf, bf), z1 = 0.f, z2 = 0.f, z3 = 0.f;
            DOT36(wf, h0s, z0, z1, z2, z3);
            zs[g] = (z0 + z1) + (z2 + z3);
            __syncthreads();
            if (g < Hn) {
                float zi = zs[g], zf = zs[g + 36], zg = zs[g + 72], zo = zs[g + 108];
                c0 = sigf(zf) * c0 + sigf(zi) * tanh_fast(zg);
                h0s[g] = sigf(zo) * tanh_fast(c0);
            } else if (g < 72) {
                h0s[g] = cbuf[j][g - 36];
            }
            __syncthreads();
            float y0 = b1, y1 = 0.f, y2 = 0.f, y3 = 0.f;
            DOT72(w1i, h0s, y0, y1, y2, y3);
            DOT36(w1h, hs1, y0, y1, y2, y3);
            zs[g] = (y0 + y1) + (y2 + y3);
            __syncthreads();
            if (g < Hn) {
                float zi = zs[g], zf = zs[g + 36], zg = zs[g + 72], zo = zs[g + 108];
                c1 = sigf(zf) * c1 + sigf(zi) * tanh_fast(zg);
                hs1[g] = sigf(zo) * tanh_fast(c1);
            }
            __syncthreads();
        }
    }

    // ---- tail ----
    float zR = bih1r[g] + bhh1r[g];
#pragma unroll
    for (int k = 0; k < 72; ++k) zR = fmaf(Wih1r[g * 72 + k], h0s[k], zR);
    zs[g] = zR;
    __syncthreads();
    if (g < Hn) {
        float zi = zs[g], zg = zs[g + 72], zo = zs[g + 108];
        float c  = sigf(zi) * tanh_fast(zg);
        float hrv = sigf(zo) * tanh_fast(c);
        red[g] = fcW[36 + g] * hrv + fcW[g] * hs1[g];
    }
    __syncthreads();
    if (g == 0) {
        float s = fcb[0];
        for (int j = 0; j < Hn; ++j) s += red[j];
        out[b] = s;
    }
}

extern "C" void kernel_launch(void* const* d_in, const int* in_sizes, int n_in,
                              void* d_out, int out_size, void* d_ws, size_t ws_size,
                              hipStream_t stream)
{
    const float* x     = (const float*)d_in[0];
    const float* Wih0f = (const float*)d_in[1];
    const float* Whh0f = (const float*)d_in[2];
    const float* bih0f = (const float*)d_in[3];
    const float* bhh0f = (const float*)d_in[4];
    const float* Wih0r = (const float*)d_in[5];
    const float* Whh0r = (const float*)d_in[6];
    const float* bih0r = (const float*)d_in[7];
    const float* bhh0r = (const float*)d_in[8];
    const float* Wih1f = (const float*)d_in[9];
    const float* Whh1f = (const float*)d_in[10];
    const float* bih1f = (const float*)d_in[11];
    const float* bhh1f = (const float*)d_in[12];
    const float* Wih1r = (const float*)d_in[13];
    const float* bih1r = (const float*)d_in[15];
    const float* bhh1r = (const float*)d_in[16];
    const float* fcW   = (const float*)d_in[17];
    const float* fcb   = (const float*)d_in[18];

    const size_t need = (size_t)BB * TT * Hn * sizeof(float);   // 151 MB
    if (d_ws != nullptr && ws_size >= need) {
        float* h0r = (float*)d_ws;
        l0rev_kernel<<<BB / CH0, NT0, 0, stream>>>(x, Wih0r, Whh0r, bih0r, bhh0r, h0r);
        fused_fwd_kernel<<<BB / CH1, NT1, 0, stream>>>(
            x, Wih0f, Whh0f, bih0f, bhh0f, Wih1f, Whh1f, bih1f, bhh1f,
            Wih1r, bih1r, bhh1r, fcW, fcb, h0r, (float*)d_out);
    } else {
        fused_all_kernel<<<BB, G4, 0, stream>>>(
            x, Wih0f, Whh0f, bih0f, bhh0f, Wih0r, Whh0r, bih0r, bhh0r,
            Wih1f, Whh1f, bih1f, bhh1f, Wih1r, bih1r, bhh1r, fcW, fcb,
            (float*)d_out);
    }
}